// Round 1
// baseline (117.406 us; speedup 1.0000x reference)
//
#include <hip/hip_runtime.h>
#include <math.h>

#define BB 4
#define CC 256
#define NN 4096
#define KK 32
#define DD 256
#define GG 8   // C/K

__device__ __forceinline__ float wredsum(float v) {
#pragma unroll
  for (int o = 32; o > 0; o >>= 1) v += __shfl_xor(v, o, 64);
  return v;
}
__device__ __forceinline__ float wredmax(float v) {
#pragma unroll
  for (int o = 32; o > 0; o >>= 1) v = fmaxf(v, __shfl_xor(v, o, 64));
  return v;
}

// Kernel 1: x_phi (grouped 1x1 conv) + softmax over n, per (b,k).
// phi layout: [b][n][k]
__global__ __launch_bounds__(256) void k_phi(const float* __restrict__ x,
                                             const float* __restrict__ wphi,
                                             float* __restrict__ phi) {
  const int b = blockIdx.x >> 5;
  const int k = blockIdx.x & 31;
  const int tid = threadIdx.x;
  const float* xb = x + (size_t)(b * CC + k * GG) * NN;
  float w[GG];
#pragma unroll
  for (int j = 0; j < GG; ++j) w[j] = wphi[k * GG + j];
  float v[16];
  float mx = -1e30f;
#pragma unroll
  for (int i = 0; i < 16; ++i) {
    const int n = i * 256 + tid;
    float s = 0.f;
#pragma unroll
    for (int j = 0; j < GG; ++j) s = fmaf(xb[(size_t)j * NN + n], w[j], s);
    v[i] = s;
    mx = fmaxf(mx, s);
  }
  __shared__ float rb[4];
  mx = wredmax(mx);
  if ((tid & 63) == 0) rb[tid >> 6] = mx;
  __syncthreads();
  mx = fmaxf(fmaxf(rb[0], rb[1]), fmaxf(rb[2], rb[3]));
  float sum = 0.f;
#pragma unroll
  for (int i = 0; i < 16; ++i) {
    v[i] = __expf(v[i] - mx);
    sum += v[i];
  }
  sum = wredsum(sum);
  __syncthreads();
  if ((tid & 63) == 0) rb[tid >> 6] = sum;
  __syncthreads();
  const float inv = 1.f / (rb[0] + rb[1] + rb[2] + rb[3]);
#pragma unroll
  for (int i = 0; i < 16; ++i) {
    const int n = i * 256 + tid;
    phi[((size_t)b * NN + n) * KK + k] = v[i] * inv;
  }
}

// Kernel 2 (used twice): outh[half][b][c][k] = sum_{n in half} x[b,c,n] * p[b,n,k]
// grid = B*32*2, block 256. c-tile of 8 channels per block.
__global__ __launch_bounds__(256) void k_xp(const float* __restrict__ x,
                                            const float* __restrict__ p,
                                            float* __restrict__ outh) {
  const int half = blockIdx.x & 1;
  const int ct = (blockIdx.x >> 1) & 31;
  const int b = blockIdx.x >> 6;
  const int tid = threadIdx.x;
  const int k = tid & 31;
  const int g = tid >> 5;  // 8 n-groups
  const int n0 = half * 2048 + g * 256;
  const float* xb = x + (size_t)(b * CC + ct * 8) * NN;
  const float* pb = p + (size_t)b * NN * KK + k;
  float acc[8] = {0.f, 0.f, 0.f, 0.f, 0.f, 0.f, 0.f, 0.f};
  for (int n = n0; n < n0 + 256; n += 4) {
    const float p0 = pb[(size_t)(n + 0) * KK];
    const float p1 = pb[(size_t)(n + 1) * KK];
    const float p2 = pb[(size_t)(n + 2) * KK];
    const float p3 = pb[(size_t)(n + 3) * KK];
#pragma unroll
    for (int c = 0; c < 8; ++c) {
      const float4 xv = *reinterpret_cast<const float4*>(xb + (size_t)c * NN + n);
      acc[c] = fmaf(xv.x, p0, acc[c]);
      acc[c] = fmaf(xv.y, p1, acc[c]);
      acc[c] = fmaf(xv.z, p2, acc[c]);
      acc[c] = fmaf(xv.w, p3, acc[c]);
    }
  }
  __shared__ float lds[8 * 8 * 32];
#pragma unroll
  for (int c = 0; c < 8; ++c) lds[(g * 8 + c) * 32 + k] = acc[c];
  __syncthreads();
  const int c2 = tid >> 5, k2 = tid & 31;
  float s = 0.f;
#pragma unroll
  for (int gg = 0; gg < 8; ++gg) s += lds[(gg * 8 + c2) * 32 + k2];
  outh[((size_t)(half * BB + b) * CC + ct * 8 + c2) * KK + k2] = s;
}

// Kernel 3: code = w_theta @ M1, normalize over d; emit bc2 = 2*s2*code, s2, t3.
__global__ __launch_bounds__(256) void k_code(const float* __restrict__ m1h,
                                              const float* __restrict__ wth,
                                              const float* __restrict__ scale,
                                              float* __restrict__ code,
                                              float* __restrict__ bc2,
                                              float* __restrict__ s2g,
                                              float* __restrict__ t3) {
  const int b = blockIdx.x >> 5;
  const int k = blockIdx.x & 31;
  const int d = threadIdx.x;
  __shared__ __align__(16) float m1s[CC];
  m1s[d] = m1h[((size_t)b * CC + d) * KK + k] +
           m1h[((size_t)(BB + b) * CC + d) * KK + k];
  __syncthreads();
  float cd = 0.f;
  const float* wt = wth + (size_t)d * CC;
#pragma unroll 4
  for (int c = 0; c < CC; c += 4) {
    const float4 w4 = *reinterpret_cast<const float4*>(wt + c);
    const float4 m4 = *reinterpret_cast<const float4*>(&m1s[c]);
    cd = fmaf(w4.x, m4.x, cd);
    cd = fmaf(w4.y, m4.y, cd);
    cd = fmaf(w4.z, m4.z, cd);
    cd = fmaf(w4.w, m4.w, cd);
  }
  __shared__ float rb[4];
  float ss = wredsum(cd * cd);
  if ((d & 63) == 0) rb[d >> 6] = ss;
  __syncthreads();
  const float nrm = sqrtf(rb[0] + rb[1] + rb[2] + rb[3]);
  const float inv = 1.f / fmaxf(nrm, 1e-12f);
  cd *= inv;
  const float sc = scale[(size_t)d * KK + k];
  const float s2 = sc * sc;
  code[((size_t)b * DD + d) * KK + k] = cd;
  bc2[((size_t)b * DD + d) * KK + k] = 2.f * s2 * cd;
  if (b == 0) s2g[(size_t)d * KK + k] = s2;
  float tt = wredsum(s2 * cd * cd);
  __syncthreads();
  if ((d & 63) == 0) rb[d >> 6] = tt;
  __syncthreads();
  if (d == 0) t3[b * KK + k] = rb[0] + rb[1] + rb[2] + rb[3];
}

// Kernel 4: dist + softmax over k -> Q (written to d_out) + per-tile Qsum partials.
// grid = B * 128 (n-tiles of 32), block 256: (nl = tid&31, dq = tid>>5 -> 32 d's each)
__global__ __launch_bounds__(256) void k_dist(const float* __restrict__ x,
                                              const float* __restrict__ s2g,
                                              const float* __restrict__ bc2,
                                              const float* __restrict__ t3,
                                              float* __restrict__ qout,
                                              float* __restrict__ qpart) {
  const int b = blockIdx.x >> 7;
  const int tile = blockIdx.x & 127;
  const int n0 = tile * 32;
  const int tid = threadIdx.x;
  const int nl = tid & 31;
  const int dq = tid >> 5;  // 0..7
  float acc[32];
#pragma unroll
  for (int k = 0; k < 32; ++k) acc[k] = 0.f;
  const float* xb = x + (size_t)(b * CC + dq * 32) * NN + n0 + nl;
  const float* s2b = s2g + (size_t)dq * 32 * KK;
  const float* bcb = bc2 + ((size_t)b * DD + dq * 32) * KK;
  for (int dd = 0; dd < 32; ++dd) {
    const float xv = xb[(size_t)dd * NN];
    const float4* s2p = reinterpret_cast<const float4*>(s2b + dd * KK);
    const float4* bcp = reinterpret_cast<const float4*>(bcb + dd * KK);
#pragma unroll
    for (int q = 0; q < 8; ++q) {
      const float4 s4 = s2p[q];
      const float4 b4 = bcp[q];
      float t;
      t = fmaf(xv, s4.x, -b4.x); acc[q * 4 + 0] = fmaf(xv, t, acc[q * 4 + 0]);
      t = fmaf(xv, s4.y, -b4.y); acc[q * 4 + 1] = fmaf(xv, t, acc[q * 4 + 1]);
      t = fmaf(xv, s4.z, -b4.z); acc[q * 4 + 2] = fmaf(xv, t, acc[q * 4 + 2]);
      t = fmaf(xv, s4.w, -b4.w); acc[q * 4 + 3] = fmaf(xv, t, acc[q * 4 + 3]);
    }
  }
  __shared__ float lds[8 * 32 * 33];  // padded: stride 33 to avoid bank conflicts
#pragma unroll
  for (int k = 0; k < 32; ++k) lds[(dq * 32 + nl) * 33 + k] = acc[k];
  __syncthreads();
  // phase 2: (nl2 = tid&31, kq = tid>>5 -> 4 k's each)
  const int nl2 = tid & 31;
  const int kq = tid >> 5;
  float vals[4];
#pragma unroll
  for (int j = 0; j < 4; ++j) {
    const int k = kq * 4 + j;
    float s = 0.f;
#pragma unroll
    for (int g = 0; g < 8; ++g) s += lds[(g * 32 + nl2) * 33 + k];
    vals[j] = -0.5f * (s + t3[b * KK + k]);
  }
  __shared__ float smax[32 * 8];
  __shared__ float ssum[32 * 8];
  float m4 = fmaxf(fmaxf(vals[0], vals[1]), fmaxf(vals[2], vals[3]));
  smax[nl2 * 8 + kq] = m4;
  __syncthreads();
  float m = smax[nl2 * 8 + 0];
#pragma unroll
  for (int g = 1; g < 8; ++g) m = fmaxf(m, smax[nl2 * 8 + g]);
  float e[4];
  float ps = 0.f;
#pragma unroll
  for (int j = 0; j < 4; ++j) {
    e[j] = __expf(vals[j] - m);
    ps += e[j];
  }
  ssum[nl2 * 8 + kq] = ps;
  __syncthreads();
  float tot = 0.f;
#pragma unroll
  for (int g = 0; g < 8; ++g) tot += ssum[nl2 * 8 + g];
  const float inv = 1.f / tot;
  float4 q4;
  q4.x = e[0] * inv; q4.y = e[1] * inv; q4.z = e[2] * inv; q4.w = e[3] * inv;
  *reinterpret_cast<float4*>(qout + ((size_t)b * NN + n0 + nl2) * KK + kq * 4) = q4;
  // per-(b,k) partial sums over this tile's 32 n's: half-wave shuffle reduce
  float qs[4] = {q4.x, q4.y, q4.z, q4.w};
#pragma unroll
  for (int j = 0; j < 4; ++j) {
    float v = qs[j];
#pragma unroll
    for (int o = 1; o < 32; o <<= 1) v += __shfl_xor(v, o, 64);
    if (nl2 == 0) qpart[((size_t)b * KK + kq * 4 + j) * 128 + tile] = v;
  }
}

// Kernel 6: Qsum reduce + Z = scale*(Znum/Qsum - code) normalized over d.
__global__ __launch_bounds__(256) void k_z(const float* __restrict__ znh,
                                           const float* __restrict__ code,
                                           const float* __restrict__ scale,
                                           const float* __restrict__ qpart,
                                           float* __restrict__ zout) {
  const int b = blockIdx.x >> 5;
  const int k = blockIdx.x & 31;
  const int d = threadIdx.x;
  __shared__ float rb[4];
  float qp = 0.f;
  if (d < 128) qp = qpart[((size_t)b * KK + k) * 128 + d];
  qp = wredsum(qp);
  if ((d & 63) == 0) rb[d >> 6] = qp;
  __syncthreads();
  const float qs = rb[0] + rb[1] + rb[2] + rb[3];
  const float zn = znh[((size_t)b * CC + d) * KK + k] +
                   znh[((size_t)(BB + b) * CC + d) * KK + k];
  const float cd = code[((size_t)b * DD + d) * KK + k];
  const float z_ = scale[(size_t)d * KK + k] * (zn / qs - cd);
  float ss = wredsum(z_ * z_);
  __syncthreads();
  if ((d & 63) == 0) rb[d >> 6] = ss;
  __syncthreads();
  const float rn = 1.f / sqrtf(rb[0] + rb[1] + rb[2] + rb[3]);
  zout[((size_t)b * DD + d) * KK + k] = z_ * rn;
}

extern "C" void kernel_launch(void* const* d_in, const int* in_sizes, int n_in,
                              void* d_out, int out_size, void* d_ws, size_t ws_size,
                              hipStream_t stream) {
  const float* x = (const float*)d_in[0];
  const float* wth = (const float*)d_in[1];
  const float* wphi = (const float*)d_in[2];
  const float* scale = (const float*)d_in[3];
  float* out = (float*)d_out;
  float* zout = out;                        // B*D*K = 32768
  float* qout = out + (size_t)BB * DD * KK; // B*N*K = 524288
  float* ws = (float*)d_ws;
  float* phi = ws;                                   // B*N*K   = 524288
  float* m1h = phi + (size_t)BB * NN * KK;           // 2*B*C*K = 65536
  float* code = m1h + 2 * (size_t)BB * CC * KK;      // B*D*K   = 32768
  float* bc2 = code + (size_t)BB * DD * KK;          // B*D*K   = 32768
  float* s2g = bc2 + (size_t)BB * DD * KK;           // D*K     = 8192
  float* t3 = s2g + (size_t)DD * KK;                 // B*K     = 128
  float* qpart = t3 + BB * KK;                       // B*K*128 = 16384
  float* znh = qpart + (size_t)BB * KK * 128;        // 2*B*C*K = 65536

  k_phi<<<BB * KK, 256, 0, stream>>>(x, wphi, phi);
  k_xp<<<BB * 32 * 2, 256, 0, stream>>>(x, phi, m1h);
  k_code<<<BB * KK, 256, 0, stream>>>(m1h, wth, scale, code, bc2, s2g, t3);
  k_dist<<<BB * 128, 256, 0, stream>>>(x, s2g, bc2, t3, qout, qpart);
  k_xp<<<BB * 32 * 2, 256, 0, stream>>>(x, qout, znh);
  k_z<<<BB * KK, 256, 0, stream>>>(znh, code, scale, qpart, zout);
}

// Round 2
// 100.775 us; speedup vs baseline: 1.1650x; 1.1650x over previous
//
#include <hip/hip_runtime.h>
#include <math.h>

#define BB 4
#define CC 256
#define NN 4096
#define KK 32
#define DD 256
#define GG 8   // C/K

__device__ __forceinline__ float wredsum(float v) {
#pragma unroll
  for (int o = 32; o > 0; o >>= 1) v += __shfl_xor(v, o, 64);
  return v;
}
__device__ __forceinline__ float wredmax(float v) {
#pragma unroll
  for (int o = 32; o > 0; o >>= 1) v = fmaxf(v, __shfl_xor(v, o, 64));
  return v;
}

// Kernel 1: x_phi (grouped 1x1 conv) + softmax over n, per (b,k).
// phi layout: [b][k][n]  (coalesced float4 reads AND writes)
__global__ __launch_bounds__(256) void k_phi(const float* __restrict__ x,
                                             const float* __restrict__ wphi,
                                             float* __restrict__ phi) {
  const int b = blockIdx.x >> 5;
  const int k = blockIdx.x & 31;
  const int tid = threadIdx.x;
  const float* xb = x + (size_t)(b * CC + k * GG) * NN;
  float w[GG];
#pragma unroll
  for (int j = 0; j < GG; ++j) w[j] = wphi[k * GG + j];
  float4 v[4];
  float mx = -1e30f;
#pragma unroll
  for (int i = 0; i < 4; ++i) {
    const int n = i * 1024 + tid * 4;
    float4 s = make_float4(0.f, 0.f, 0.f, 0.f);
#pragma unroll
    for (int j = 0; j < GG; ++j) {
      const float4 xv = *reinterpret_cast<const float4*>(xb + (size_t)j * NN + n);
      s.x = fmaf(xv.x, w[j], s.x);
      s.y = fmaf(xv.y, w[j], s.y);
      s.z = fmaf(xv.z, w[j], s.z);
      s.w = fmaf(xv.w, w[j], s.w);
    }
    v[i] = s;
    mx = fmaxf(mx, fmaxf(fmaxf(s.x, s.y), fmaxf(s.z, s.w)));
  }
  __shared__ float rb[4];
  mx = wredmax(mx);
  if ((tid & 63) == 0) rb[tid >> 6] = mx;
  __syncthreads();
  mx = fmaxf(fmaxf(rb[0], rb[1]), fmaxf(rb[2], rb[3]));
  float sum = 0.f;
#pragma unroll
  for (int i = 0; i < 4; ++i) {
    v[i].x = __expf(v[i].x - mx);
    v[i].y = __expf(v[i].y - mx);
    v[i].z = __expf(v[i].z - mx);
    v[i].w = __expf(v[i].w - mx);
    sum += v[i].x + v[i].y + v[i].z + v[i].w;
  }
  sum = wredsum(sum);
  __syncthreads();
  if ((tid & 63) == 0) rb[tid >> 6] = sum;
  __syncthreads();
  const float inv = 1.f / (rb[0] + rb[1] + rb[2] + rb[3]);
  float* pk = phi + (size_t)(b * KK + k) * NN;
#pragma unroll
  for (int i = 0; i < 4; ++i) {
    const int n = i * 1024 + tid * 4;
    float4 o;
    o.x = v[i].x * inv; o.y = v[i].y * inv; o.z = v[i].z * inv; o.w = v[i].w * inv;
    *reinterpret_cast<float4*>(pk + n) = o;
  }
}

// Kernel 2 (x2): outq[quarter][b][c][k] = sum_{n in quarter} x[b,c,n] * p[...]
// PLAYOUT 0: p is [b][k][n] (phi). PLAYOUT 1: p is [b][n][k] (Q).
// grid = B*32*4, block 256. c-tile of 8 channels per block, quarter = 1024 n's.
template <int PLAYOUT>
__global__ __launch_bounds__(256) void k_xp(const float* __restrict__ x,
                                            const float* __restrict__ p,
                                            float* __restrict__ outq) {
  const int quarter = blockIdx.x & 3;
  const int ct = (blockIdx.x >> 2) & 31;
  const int b = blockIdx.x >> 7;
  const int tid = threadIdx.x;
  const int k = tid & 31;
  const int g = tid >> 5;  // 8 n-groups of 128
  const int n0 = quarter * 1024 + g * 128;
  const float* xb = x + (size_t)(b * CC + ct * 8) * NN;
  const float* pb = (PLAYOUT == 0) ? (p + (size_t)(b * KK + k) * NN)
                                   : (p + (size_t)b * NN * KK + k);
  float acc[8] = {0.f, 0.f, 0.f, 0.f, 0.f, 0.f, 0.f, 0.f};
  for (int n = n0; n < n0 + 128; n += 4) {
    float p0, p1, p2, p3;
    if (PLAYOUT == 0) {
      const float4 pv = *reinterpret_cast<const float4*>(pb + n);
      p0 = pv.x; p1 = pv.y; p2 = pv.z; p3 = pv.w;
    } else {
      p0 = pb[(size_t)(n + 0) * KK];
      p1 = pb[(size_t)(n + 1) * KK];
      p2 = pb[(size_t)(n + 2) * KK];
      p3 = pb[(size_t)(n + 3) * KK];
    }
#pragma unroll
    for (int c = 0; c < 8; ++c) {
      const float4 xv = *reinterpret_cast<const float4*>(xb + (size_t)c * NN + n);
      acc[c] = fmaf(xv.x, p0, acc[c]);
      acc[c] = fmaf(xv.y, p1, acc[c]);
      acc[c] = fmaf(xv.z, p2, acc[c]);
      acc[c] = fmaf(xv.w, p3, acc[c]);
    }
  }
  __shared__ float lds[8 * 8 * 32];
#pragma unroll
  for (int c = 0; c < 8; ++c) lds[(g * 8 + c) * 32 + k] = acc[c];
  __syncthreads();
  const int c2 = tid >> 5, k2 = tid & 31;
  float s = 0.f;
#pragma unroll
  for (int gg = 0; gg < 8; ++gg) s += lds[(gg * 8 + c2) * 32 + k2];
  outq[((size_t)(quarter * BB + b) * CC + ct * 8 + c2) * KK + k2] = s;
}

// Kernel 3: code = w_theta @ M1, normalize over d; emit bc2 = 2*s2*code, s2, t3.
__global__ __launch_bounds__(256) void k_code(const float* __restrict__ m1q,
                                              const float* __restrict__ wth,
                                              const float* __restrict__ scale,
                                              float* __restrict__ code,
                                              float* __restrict__ bc2,
                                              float* __restrict__ s2g,
                                              float* __restrict__ t3) {
  const int b = blockIdx.x >> 5;
  const int k = blockIdx.x & 31;
  const int d = threadIdx.x;
  __shared__ __align__(16) float m1s[CC];
  float m = 0.f;
#pragma unroll
  for (int q = 0; q < 4; ++q)
    m += m1q[((size_t)(q * BB + b) * CC + d) * KK + k];
  m1s[d] = m;
  __syncthreads();
  float cd = 0.f;
  const float* wt = wth + (size_t)d * CC;
#pragma unroll 4
  for (int c = 0; c < CC; c += 4) {
    const float4 w4 = *reinterpret_cast<const float4*>(wt + c);
    const float4 m4 = *reinterpret_cast<const float4*>(&m1s[c]);
    cd = fmaf(w4.x, m4.x, cd);
    cd = fmaf(w4.y, m4.y, cd);
    cd = fmaf(w4.z, m4.z, cd);
    cd = fmaf(w4.w, m4.w, cd);
  }
  __shared__ float rb[4];
  float ss = wredsum(cd * cd);
  if ((d & 63) == 0) rb[d >> 6] = ss;
  __syncthreads();
  const float nrm = sqrtf(rb[0] + rb[1] + rb[2] + rb[3]);
  const float inv = 1.f / fmaxf(nrm, 1e-12f);
  cd *= inv;
  const float sc = scale[(size_t)d * KK + k];
  const float s2 = sc * sc;
  code[((size_t)b * DD + d) * KK + k] = cd;
  bc2[((size_t)b * DD + d) * KK + k] = 2.f * s2 * cd;
  if (b == 0) s2g[(size_t)d * KK + k] = s2;
  float tt = wredsum(s2 * cd * cd);
  __syncthreads();
  if ((d & 63) == 0) rb[d >> 6] = tt;
  __syncthreads();
  if (d == 0) t3[b * KK + k] = rb[0] + rb[1] + rb[2] + rb[3];
}

// Kernel 4: dist + softmax over k -> Q (written to d_out) + per-tile Qsum partials.
// grid = B * 128 (n-tiles of 32), block 256: (nl = tid&31, dq = tid>>5 -> 32 d's each)
__global__ __launch_bounds__(256) void k_dist(const float* __restrict__ x,
                                              const float* __restrict__ s2g,
                                              const float* __restrict__ bc2,
                                              const float* __restrict__ t3,
                                              float* __restrict__ qout,
                                              float* __restrict__ qpart) {
  const int b = blockIdx.x >> 7;
  const int tile = blockIdx.x & 127;
  const int n0 = tile * 32;
  const int tid = threadIdx.x;
  const int nl = tid & 31;
  const int dq = tid >> 5;  // 0..7
  float acc[32];
#pragma unroll
  for (int k = 0; k < 32; ++k) acc[k] = 0.f;
  const float* xb = x + (size_t)(b * CC + dq * 32) * NN + n0 + nl;
  const float* s2b = s2g + (size_t)dq * 32 * KK;
  const float* bcb = bc2 + ((size_t)b * DD + dq * 32) * KK;
  for (int dd = 0; dd < 32; ++dd) {
    const float xv = xb[(size_t)dd * NN];
    const float4* s2p = reinterpret_cast<const float4*>(s2b + dd * KK);
    const float4* bcp = reinterpret_cast<const float4*>(bcb + dd * KK);
#pragma unroll
    for (int q = 0; q < 8; ++q) {
      const float4 s4 = s2p[q];
      const float4 b4 = bcp[q];
      float t;
      t = fmaf(xv, s4.x, -b4.x); acc[q * 4 + 0] = fmaf(xv, t, acc[q * 4 + 0]);
      t = fmaf(xv, s4.y, -b4.y); acc[q * 4 + 1] = fmaf(xv, t, acc[q * 4 + 1]);
      t = fmaf(xv, s4.z, -b4.z); acc[q * 4 + 2] = fmaf(xv, t, acc[q * 4 + 2]);
      t = fmaf(xv, s4.w, -b4.w); acc[q * 4 + 3] = fmaf(xv, t, acc[q * 4 + 3]);
    }
  }
  __shared__ float lds[8 * 32 * 33];  // padded: stride 33 to avoid bank conflicts
#pragma unroll
  for (int k = 0; k < 32; ++k) lds[(dq * 32 + nl) * 33 + k] = acc[k];
  __syncthreads();
  // phase 2: (nl2 = tid&31, kq = tid>>5 -> 4 k's each)
  const int nl2 = tid & 31;
  const int kq = tid >> 5;
  float vals[4];
#pragma unroll
  for (int j = 0; j < 4; ++j) {
    const int k = kq * 4 + j;
    float s = 0.f;
#pragma unroll
    for (int g = 0; g < 8; ++g) s += lds[(g * 32 + nl2) * 33 + k];
    vals[j] = -0.5f * (s + t3[b * KK + k]);
  }
  __shared__ float smax[32 * 8];
  __shared__ float ssum[32 * 8];
  float m4 = fmaxf(fmaxf(vals[0], vals[1]), fmaxf(vals[2], vals[3]));
  smax[nl2 * 8 + kq] = m4;
  __syncthreads();
  float m = smax[nl2 * 8 + 0];
#pragma unroll
  for (int g = 1; g < 8; ++g) m = fmaxf(m, smax[nl2 * 8 + g]);
  float e[4];
  float ps = 0.f;
#pragma unroll
  for (int j = 0; j < 4; ++j) {
    e[j] = __expf(vals[j] - m);
    ps += e[j];
  }
  ssum[nl2 * 8 + kq] = ps;
  __syncthreads();
  float tot = 0.f;
#pragma unroll
  for (int g = 0; g < 8; ++g) tot += ssum[nl2 * 8 + g];
  const float inv = 1.f / tot;
  float4 q4;
  q4.x = e[0] * inv; q4.y = e[1] * inv; q4.z = e[2] * inv; q4.w = e[3] * inv;
  *reinterpret_cast<float4*>(qout + ((size_t)b * NN + n0 + nl2) * KK + kq * 4) = q4;
  // per-(b,k) partial sums over this tile's 32 n's: half-wave shuffle reduce
  float qs[4] = {q4.x, q4.y, q4.z, q4.w};
#pragma unroll
  for (int j = 0; j < 4; ++j) {
    float v = qs[j];
#pragma unroll
    for (int o = 1; o < 32; o <<= 1) v += __shfl_xor(v, o, 64);
    if (nl2 == 0) qpart[((size_t)b * KK + kq * 4 + j) * 128 + tile] = v;
  }
}

// Kernel 6: Qsum reduce + Z = scale*(Znum/Qsum - code) normalized over d.
__global__ __launch_bounds__(256) void k_z(const float* __restrict__ znq,
                                           const float* __restrict__ code,
                                           const float* __restrict__ scale,
                                           const float* __restrict__ qpart,
                                           float* __restrict__ zout) {
  const int b = blockIdx.x >> 5;
  const int k = blockIdx.x & 31;
  const int d = threadIdx.x;
  __shared__ float rb[4];
  float qp = 0.f;
  if (d < 128) qp = qpart[((size_t)b * KK + k) * 128 + d];
  qp = wredsum(qp);
  if ((d & 63) == 0) rb[d >> 6] = qp;
  __syncthreads();
  const float qs = rb[0] + rb[1] + rb[2] + rb[3];
  float zn = 0.f;
#pragma unroll
  for (int q = 0; q < 4; ++q)
    zn += znq[((size_t)(q * BB + b) * CC + d) * KK + k];
  const float cd = code[((size_t)b * DD + d) * KK + k];
  const float z_ = scale[(size_t)d * KK + k] * (zn / qs - cd);
  float ss = wredsum(z_ * z_);
  __syncthreads();
  if ((d & 63) == 0) rb[d >> 6] = ss;
  __syncthreads();
  const float rn = 1.f / sqrtf(rb[0] + rb[1] + rb[2] + rb[3]);
  zout[((size_t)b * DD + d) * KK + k] = z_ * rn;
}

extern "C" void kernel_launch(void* const* d_in, const int* in_sizes, int n_in,
                              void* d_out, int out_size, void* d_ws, size_t ws_size,
                              hipStream_t stream) {
  const float* x = (const float*)d_in[0];
  const float* wth = (const float*)d_in[1];
  const float* wphi = (const float*)d_in[2];
  const float* scale = (const float*)d_in[3];
  float* out = (float*)d_out;
  float* zout = out;                        // B*D*K = 32768
  float* qout = out + (size_t)BB * DD * KK; // B*N*K = 524288
  float* ws = (float*)d_ws;
  float* phi = ws;                                   // B*K*N   = 524288
  float* m1q = phi + (size_t)BB * NN * KK;           // 4*B*C*K = 131072
  float* code = m1q + 4 * (size_t)BB * CC * KK;      // B*D*K   = 32768
  float* bc2 = code + (size_t)BB * DD * KK;          // B*D*K   = 32768
  float* s2g = bc2 + (size_t)BB * DD * KK;           // D*K     = 8192
  float* t3 = s2g + (size_t)DD * KK;                 // B*K     = 128
  float* qpart = t3 + BB * KK;                       // B*K*128 = 16384
  float* znq = qpart + (size_t)BB * KK * 128;        // 4*B*C*K = 131072

  k_phi<<<BB * KK, 256, 0, stream>>>(x, wphi, phi);
  k_xp<0><<<BB * 32 * 4, 256, 0, stream>>>(x, phi, m1q);
  k_code<<<BB * KK, 256, 0, stream>>>(m1q, wth, scale, code, bc2, s2g, t3);
  k_dist<<<BB * 128, 256, 0, stream>>>(x, s2g, bc2, t3, qout, qpart);
  k_xp<1><<<BB * 32 * 4, 256, 0, stream>>>(x, qout, znq);
  k_z<<<BB * KK, 256, 0, stream>>>(znq, code, scale, qpart, zout);
}